// Round 2
// baseline (2880.014 us; speedup 1.0000x reference)
//
#include <hip/hip_runtime.h>

constexpr int NS   = 32;
constexpr int C    = 16;
constexpr int H    = 128;
constexpr int W    = 128;
constexpr int DS   = 5;
constexpr int M    = C * DS * DS;   // 400
constexpr int NLAG = 81;            // 9x9 lags

// ---------------------------------------------------------------------------
// autocorr: R[((n*C+i)*C+j)*81 + u*9 + v] = sum_{h,w} x[n,i,h,w]*x[n,j,h+u-4,w+v-4]
// wg = (n, jg) with jg = group of 2 j-channels
// 256 threads = (i:16 [bits 7:4], j:2 [bit 3], hh:4 [bits 2:1], wh:2 [bit 0])
// ---------------------------------------------------------------------------
constexpr int PITCH = 140;   // words; 140*4B % 16 == 0 -> aligned b128 rows
constexpr int HROWS = 24;    // 16 strip rows + 8 halo

__global__ __launch_bounds__(256, 1)
void autocorr_kernel(const float* __restrict__ x, float* __restrict__ R)
{
    __shared__ float xj[2 * HROWS * PITCH];   // ~26.9 KB

    const int n   = blockIdx.x;
    const int jg  = blockIdx.y;               // 0..7
    const int tid = threadIdx.x;
    const int i   = tid >> 4;                 // 0..15  (bits 7:4)
    const int j   = (tid >> 3) & 1;           // 0..1   (bit 3)
    const int hh  = (tid >> 1) & 3;           // 0..3   (bits 2:1)
    const int wh  = tid & 1;                  // 0..1   (bit 0)

    float acc[NLAG];
#pragma unroll
    for (int l = 0; l < NLAG; ++l) acc[l] = 0.f;

    const float* xn = x + (size_t)n * C * H * W;
    const float* xi = xn + (size_t)i * H * W;

    for (int s = 0; s < 8; ++s) {
        const int h0 = s * 16;
        __syncthreads();   // protect LDS reuse across strips
        // stage 2 j-channels, rows h0-4..h0+19, cols padded +-4 (zeros)
        for (int idx = tid; idx < 2 * HROWS * 32; idx += 256) {
            int cj  = idx / (HROWS * 32);
            int rem = idx - cj * (HROWS * 32);
            int rr  = rem >> 5;
            int wc  = rem & 31;
            int r   = h0 - 4 + rr;
            float4 v = make_float4(0.f, 0.f, 0.f, 0.f);
            if (r >= 0 && r < H)
                v = ((const float4*)(xn + ((size_t)(jg * 2 + cj) * H + r) * W))[wc];
            *(float4*)(&xj[(cj * HROWS + rr) * PITCH + 4 + wc * 4]) = v;
        }
        for (int idx = tid; idx < 2 * HROWS; idx += 256) {
            float* row = &xj[idx * PITCH];
            row[0] = 0.f; row[1] = 0.f; row[2] = 0.f; row[3] = 0.f;
            row[132] = 0.f; row[133] = 0.f; row[134] = 0.f; row[135] = 0.f;
        }
        __syncthreads();

        for (int rr = 0; rr < 4; ++rr) {
            const int r    = h0 + hh * 4 + rr;
            const int ldsr = hh * 4 + rr;      // r - h0
            const float* xrow = xi + (size_t)r * W;
            for (int wc = 0; wc < 16; ++wc) {
                const int wb = (wc * 2 + wh) * 4;   // interleaved halves for bank spread
                const float4 a4 = *(const float4*)(xrow + wb);
                const float av[4] = {a4.x, a4.y, a4.z, a4.w};
#pragma unroll
                for (int du = 0; du < 9; ++du) {
                    const float* brow = &xj[(j * HROWS + ldsr + du) * PITCH + wb];
                    const float4 b0 = *(const float4*)(brow);
                    const float4 b1 = *(const float4*)(brow + 4);
                    const float4 b2 = *(const float4*)(brow + 8);
                    const float bv[12] = {b0.x, b0.y, b0.z, b0.w,
                                          b1.x, b1.y, b1.z, b1.w,
                                          b2.x, b2.y, b2.z, b2.w};
#pragma unroll
                    for (int l = 0; l < 4; ++l)
#pragma unroll
                        for (int dv = 0; dv < 9; ++dv)
                            acc[du * 9 + dv] += av[l] * bv[l + dv];
                }
            }
        }
    }

    // reduce over 8 lanes (hh,wh) sharing (i,j); groups start at multiples of 8
#pragma unroll
    for (int l = 0; l < NLAG; ++l) {
        float v = acc[l];
        v += __shfl_down(v, 4);
        v += __shfl_down(v, 2);
        v += __shfl_down(v, 1);
        acc[l] = v;
    }
    if ((tid & 7) == 0) {
        float* Ro = R + (((size_t)n * C + i) * C + (jg * 2 + j)) * NLAG;
#pragma unroll
        for (int l = 0; l < NLAG; ++l) Ro[l] = acc[l];
    }
}

// ---------------------------------------------------------------------------
// crosscorr: P[(n*C+j)*25 + u*5 + v] = sum_{h,w} y[n,0,h,w]*x[n,j,h+u-2,w+v-2]
// ---------------------------------------------------------------------------
__global__ __launch_bounds__(256, 1)
void crosscorr_kernel(const float* __restrict__ x, const float* __restrict__ y,
                      float* __restrict__ P)
{
    const int n = blockIdx.x, j = blockIdx.y, tid = threadIdx.x;
    float acc[25];
#pragma unroll
    for (int l = 0; l < 25; ++l) acc[l] = 0.f;

    const float* yn = y + (size_t)n * H * W;
    const float* xc = x + ((size_t)n * C + j) * H * W;

    for (int p = tid; p < H * W; p += 256) {
        int h = p >> 7, w = p & 127;
        float yv = yn[p];
#pragma unroll
        for (int u = 0; u < 5; ++u) {
            int hr = h + u - 2;
            if ((unsigned)hr < (unsigned)H) {
#pragma unroll
                for (int v = 0; v < 5; ++v) {
                    int wc = w + v - 2;
                    if ((unsigned)wc < (unsigned)W)
                        acc[u * 5 + v] += yv * xc[hr * W + wc];
                }
            }
        }
    }
    __shared__ float red[4][25];
    int lane = tid & 63, wv = tid >> 6;
#pragma unroll
    for (int l = 0; l < 25; ++l) {
        float v = acc[l];
#pragma unroll
        for (int off = 32; off; off >>= 1) v += __shfl_down(v, off);
        if (lane == 0) red[wv][l] = v;
    }
    __syncthreads();
    if (tid < 25)
        P[((size_t)n * C + j) * 25 + tid] = red[0][tid] + red[1][tid] + red[2][tid] + red[3][tid];
}

// ---------------------------------------------------------------------------
// CG solve per sample: (Q + aI) z = P + a*dprev, Q[(i,a,b),(j,c,d)] = R[i,j,4+c-a,4+d-b]
// ---------------------------------------------------------------------------
__device__ __forceinline__ float block_sum512(float v, float* red, int tid)
{
#pragma unroll
    for (int off = 32; off; off >>= 1) v += __shfl_down(v, off);
    if ((tid & 63) == 0) red[tid >> 6] = v;
    __syncthreads();
    float s = red[0] + red[1] + red[2] + red[3] + red[4] + red[5] + red[6] + red[7];
    __syncthreads();
    return s;
}

__global__ __launch_bounds__(512, 1)
void cg_kernel(const float* __restrict__ R, const float* __restrict__ P,
               const float* __restrict__ dprev, const float* __restrict__ alpha,
               const float* __restrict__ reg, float* __restrict__ Dout, int iters)
{
    __shared__ float zv[M], rv[M], pv[M];
    __shared__ float red[8];
    const int n = blockIdx.x, t = threadIdx.x;
    const float a = alpha[n] * (float)(H * W) * reg[0] / (float)(DS * DS * C);
    const int i = t / 25, ab = t - i * 25, ar = ab / 5, br = ab - ar * 5;
    const float* Rn = R + (size_t)n * C * C * NLAG;

    if (t < M) {
        float rhs = P[(size_t)n * M + t] + a * dprev[(size_t)n * M + t];
        zv[t] = 0.f; rv[t] = rhs; pv[t] = rhs;
    }
    __syncthreads();
    float rr = block_sum512((t < M) ? rv[t] * rv[t] : 0.f, red, t);

    for (int it = 0; it < iters; ++it) {
        float ap = 0.f;
        if (t < M) {
            ap = a * pv[t];
            const float* Ri = Rn + (size_t)i * C * NLAG;
            for (int jj = 0; jj < C; ++jj) {
                const float* Rij = Ri + jj * NLAG;
                const float* pj  = pv + jj * 25;
#pragma unroll
                for (int c = 0; c < 5; ++c) {
                    const int base = (4 + c - ar) * 9 + (4 - br);
#pragma unroll
                    for (int d = 0; d < 5; ++d)
                        ap += Rij[base + d] * pj[c * 5 + d];
                }
            }
        }
        float pAp = block_sum512((t < M) ? pv[t] * ap : 0.f, red, t);
        float al  = (pAp > 1e-30f) ? rr / pAp : 0.f;
        float rn  = 0.f;
        if (t < M) {
            zv[t] += al * pv[t];
            float r2 = rv[t] - al * ap;
            rv[t] = r2;
            rn = r2 * r2;
        }
        float rrn = block_sum512(rn, red, t);
        float be  = (rr > 1e-30f) ? rrn / rr : 0.f;
        rr = rrn;
        if (t < M) pv[t] = rv[t] + be * pv[t];
        __syncthreads();
    }
    if (t < M) Dout[(size_t)n * M + t] = zv[t];
}

// ---------------------------------------------------------------------------
// tiny CNN: h0 = [D2 (16ch), 1/sqrt(beta) (1ch)] 5x5; 6 conv3x3, relu on 1..5,
// residual + h0[:16] after conv6
// ---------------------------------------------------------------------------
__global__ __launch_bounds__(512, 1)
void cnn_kernel(const float* __restrict__ D2, const float* __restrict__ beta,
                const float* __restrict__ w1, const float* __restrict__ b1,
                const float* __restrict__ w2, const float* __restrict__ b2,
                const float* __restrict__ w3, const float* __restrict__ b3,
                const float* __restrict__ w4, const float* __restrict__ b4,
                const float* __restrict__ w5, const float* __restrict__ b5,
                const float* __restrict__ w6, const float* __restrict__ b6,
                float* __restrict__ out)
{
    const int n = blockIdx.x, t = threadIdx.x;
    __shared__ float h0[17 * 25];
    __shared__ float bufA[16 * 25], bufB[16 * 25];
    __shared__ float wl[16 * 17 * 9];
    __shared__ float bl[16];

    if (t < 400)       h0[t] = D2[(size_t)n * M + t];
    else if (t < 425)  h0[t] = rsqrtf(beta[n]);
    __syncthreads();

    const float* ws[6] = {w1, w2, w3, w4, w5, w6};
    const float* bs[6] = {b1, b2, b3, b4, b5, b6};

    for (int l = 0; l < 6; ++l) {
        const int cin = (l == 0) ? 17 : 16;
        const int wsz = 16 * cin * 9;
        for (int idx = t; idx < wsz; idx += 512) wl[idx] = ws[l][idx];
        if (t < 16) bl[t] = bs[l][t];
        __syncthreads();

        const float* in = (l == 0) ? h0 : ((l & 1) ? bufA : bufB);
        float s = 0.f;
        if (t < 400) {
            const int o = t / 25, yy = (t % 25) / 5, xx = t % 5;
            s = bl[o];
            const float* wo = wl + o * cin * 9;
            for (int ci = 0; ci < cin; ++ci) {
                const float* ic = in + ci * 25;
#pragma unroll
                for (int ky = 0; ky < 3; ++ky) {
                    int iy = yy + ky - 1;
                    if ((unsigned)iy < 5u) {
#pragma unroll
                        for (int kx = 0; kx < 3; ++kx) {
                            int ix = xx + kx - 1;
                            if ((unsigned)ix < 5u)
                                s += wo[ci * 9 + ky * 3 + kx] * ic[iy * 5 + ix];
                        }
                    }
                }
            }
            if (l < 5) s = fmaxf(s, 0.f);
            else       s += h0[t];          // residual, channels 0..15 of h0
        }
        __syncthreads();   // all reads of `in`/`wl` done before overwrite
        if (t < 400) {
            if (l == 5) out[(size_t)n * M + t] = s;
            else if (l & 1) bufB[t] = s;     // l=1 -> B (read by l=2)
            else            bufA[t] = s;     // l=0,2,4 -> A (read by l=1,3,5)
        }
        __syncthreads();
    }
}

// ---------------------------------------------------------------------------
extern "C" void kernel_launch(void* const* d_in, const int* in_sizes, int n_in,
                              void* d_out, int out_size, void* d_ws, size_t ws_size,
                              hipStream_t stream)
{
    (void)in_sizes; (void)n_in; (void)out_size; (void)ws_size;
    const float* x1    = (const float*)d_in[0];
    const float* x2    = (const float*)d_in[1];
    const float* d0    = (const float*)d_in[2];
    const float* y1    = (const float*)d_in[3];
    const float* y2    = (const float*)d_in[4];
    const float* alpha = (const float*)d_in[5];
    const float* beta  = (const float*)d_in[6];
    const float* reg   = (const float*)d_in[7];
    const float* w1 = (const float*)d_in[8];  const float* b1 = (const float*)d_in[9];
    const float* w2 = (const float*)d_in[10]; const float* b2 = (const float*)d_in[11];
    const float* w3 = (const float*)d_in[12]; const float* b3 = (const float*)d_in[13];
    const float* w4 = (const float*)d_in[14]; const float* b4 = (const float*)d_in[15];
    const float* w5 = (const float*)d_in[16]; const float* b5 = (const float*)d_in[17];
    const float* w6 = (const float*)d_in[18]; const float* b6 = (const float*)d_in[19];
    float* out = (float*)d_out;

    float* ws = (float*)d_ws;
    const size_t RSZ = (size_t)NS * C * C * NLAG;   // 663552
    float* R1 = ws;
    float* R2 = R1 + RSZ;
    float* P1 = R2 + RSZ;
    float* P2 = P1 + (size_t)NS * M;
    float* D1 = P2 + (size_t)NS * M;
    float* D2 = D1 + (size_t)NS * M;

    autocorr_kernel<<<dim3(NS, 8), 256, 0, stream>>>(x1, R1);
    autocorr_kernel<<<dim3(NS, 8), 256, 0, stream>>>(x2, R2);
    crosscorr_kernel<<<dim3(NS, C), 256, 0, stream>>>(x1, y1, P1);
    crosscorr_kernel<<<dim3(NS, C), 256, 0, stream>>>(x2, y2, P2);
    cg_kernel<<<NS, 512, 0, stream>>>(R1, P1, d0, alpha, reg, D1, 25);
    cg_kernel<<<NS, 512, 0, stream>>>(R2, P2, D1, alpha, reg, D2, 25);
    cnn_kernel<<<NS, 512, 0, stream>>>(D2, beta, w1, b1, w2, b2, w3, b3,
                                       w4, b4, w5, b5, w6, b6, out);
}

// Round 3
// 884.417 us; speedup vs baseline: 3.2564x; 3.2564x over previous
//
#include <hip/hip_runtime.h>

constexpr int NS   = 32;
constexpr int C    = 16;
constexpr int H    = 128;
constexpr int W    = 128;
constexpr int DS   = 5;
constexpr int M    = C * DS * DS;   // 400
constexpr int NLAG = 81;            // 9x9 lags

typedef short short8 __attribute__((ext_vector_type(8)));   // 8 bf16 (4 VGPRs)
typedef float f32x4 __attribute__((ext_vector_type(4)));

// ---------------------------------------------------------------------------
// MFMA autocorr.  R[((n*C+i)*C+j)*81 + u*9 + v] = sum_{h,w} x[n,i,h,w]*x[n,j,h+u-4,w+v-4]
// Block = (n, v, input).  A-operand carries the v-shift (shift 4-v, so that
// pairs are x_i[w'+4-v]*x_j[w'] = target with v'=v); B carries the u row-shift.
// 4 waves split the 4 W-chunks of 32 pixels; 9 u-tiles accumulated per wave.
// LDS: 16-row ring, 16 ch per row, CH_STRIDE=152 bf16 (304B == 3 mod 8 in
// 16B-groups -> uniform 8 lanes/group for b128 = no extra bank conflicts).
// Row layout per channel: [4 pad][4 zero halo][128 data][4 zero halo][12 pad]
// so the main data starts 16B-aligned and the zero halos implement x_i OOB=0.
// ---------------------------------------------------------------------------
constexpr int CH_STRIDE_U  = 152;                 // ushorts
constexpr int ROW_STRIDE_U = 16 * CH_STRIDE_U;    // 2432 ushorts per ring row
constexpr int RING_U       = 16 * ROW_STRIDE_U;   // 38912 ushorts = 76 KiB

__device__ __forceinline__ unsigned short f2bf(float f) {
    unsigned int u = __float_as_uint(f);
    u += 0x7fffu + ((u >> 16) & 1u);   // RNE
    return (unsigned short)(u >> 16);
}

__device__ __forceinline__ void stage4(const float* __restrict__ xn,
                                       unsigned short* ring, int r0, int tid) {
    // rows r0..r0+3, 16 channels; 4 threads per (row,ch), 32 floats each
    const int p    = tid >> 2;        // 0..63
    const int sub  = tid & 3;         // 0..3 (w block of 32)
    const int row  = r0 + (p >> 4);
    const int ch   = p & 15;
    const int slot = (row + 16) & 15;
    unsigned short* dst = ring + slot * ROW_STRIDE_U + ch * CH_STRIDE_U + 8 + sub * 32;
    if (row >= 0 && row < H) {
        const float4* src = (const float4*)(xn + ((size_t)ch * H + row) * W + sub * 32);
#pragma unroll
        for (int g = 0; g < 8; ++g) {
            float4 v = src[g];
            ushort4 o;
            o.x = f2bf(v.x); o.y = f2bf(v.y); o.z = f2bf(v.z); o.w = f2bf(v.w);
            *(ushort4*)(dst + g * 4) = o;
        }
    } else {
        const ushort4 z = {0, 0, 0, 0};
#pragma unroll
        for (int g = 0; g < 8; ++g) *(ushort4*)(dst + g * 4) = z;
    }
}

__global__ __launch_bounds__(256, 1)
void autocorr_mfma(const float* __restrict__ x1, const float* __restrict__ x2,
                   float* __restrict__ R1, float* __restrict__ R2)
{
    __shared__ unsigned short ring[RING_U];

    const int n   = blockIdx.x;
    const int v   = blockIdx.y;          // 0..8 (fixed per block)
    const int zi  = blockIdx.z;          // input select
    const int tid = threadIdx.x;
    const int lane = tid & 63;
    const int wid  = tid >> 6;           // 0..3 -> W chunk
    const int w0   = wid * 32;
    const int q    = lane >> 4;          // k-octet 0..3
    const int mi   = lane & 15;          // i for A, j for B

    const float* xn = (zi ? x2 : x1) + (size_t)n * C * H * W;
    float* R        = (zi ? R2 : R1);

    // uniform v-shift selection constants (A window = x_i[w0+k+4-v])
    const int off_w  = (v >= 4) ? -8 : 0;            // ushort offset of 32B read window
    const int s_byte = (v >= 4) ? (24 - 2 * v) : (8 - 2 * v);
    const int q4     = s_byte >> 2;
    const int sh     = (s_byte & 3) * 8;             // 0 or 16

    f32x4 acc[9];
#pragma unroll
    for (int u = 0; u < 9; ++u) acc[u] = (f32x4){0.f, 0.f, 0.f, 0.f};

    // zero the 4-col halos (cc 4..7 and 136..139) of every ring row once
    for (int idx = tid; idx < 16 * 16 * 8; idx += 256) {
        int r = idx >> 7, rem = idx & 127;
        int c = rem >> 3, k = rem & 7;
        int cc = (k < 4) ? (4 + k) : (132 + k);      // 4..7, 136..139
        ring[r * ROW_STRIDE_U + c * CH_STRIDE_U + cc] = 0;
    }
    stage4(xn, ring, -4, tid);
    stage4(xn, ring, 0, tid);
    stage4(xn, ring, 4, tid);
    __syncthreads();

    for (int s = 0; s < H; s += 4) {
        stage4(xn, ring, s + 8, tid);   // slots (s+8..s+11)&15: disjoint from reads below

#pragma unroll
        for (int r4 = 0; r4 < 4; ++r4) {
            const int row   = s + r4;
            const int aslot = row & 15;
            // ---- A fragment: x_i[row, w0 + k + 4 - v] via 2 aligned b128 + funnel
            const unsigned short* arow = ring + aslot * ROW_STRIDE_U + mi * CH_STRIDE_U;
            const uint4* pa = (const uint4*)(arow + 8 + w0 + 8 * q + off_w);
            uint4 lo = pa[0], hi = pa[1];
            unsigned int d[8] = {lo.x, lo.y, lo.z, lo.w, hi.x, hi.y, hi.z, hi.w};
            union { unsigned int u[4]; short8 s8; } af;
#pragma unroll
            for (int wri = 0; wri < 4; ++wri)
                af.u[wri] = sh ? ((d[q4 + wri] >> sh) | (d[q4 + wri + 1] << 16))
                               : d[q4 + wri];
            // ---- 9 u-tiles: B = x_j[row+u-4, w0+k] (aligned b128)
#pragma unroll
            for (int u = 0; u < 9; ++u) {
                const int bslot = (row + u - 4 + 16) & 15;
                const short8 bf = *(const short8*)(ring + bslot * ROW_STRIDE_U +
                                                   mi * CH_STRIDE_U + 8 + w0 + 8 * q);
                acc[u] = __builtin_amdgcn_mfma_f32_16x16x32_bf16(af.s8, bf, acc[u], 0, 0, 0);
            }
        }
        __syncthreads();
    }

    // cross-wave reduce (4 partial copies) via ring reused as f32 scratch
    float* red = (float*)ring;           // 4*9*256 f32 = 36 KB <= 76 KB
#pragma unroll
    for (int u = 0; u < 9; ++u)
#pragma unroll
        for (int r = 0; r < 4; ++r)
            red[(wid * 9 + u) * 256 + (q * 4 + r) * 16 + mi] = acc[u][r];
    __syncthreads();

    // tid -> (i = tid>>4, j = tid&15); D[row=i][col=j]
    float* Ro = R + ((size_t)(n * C + (tid >> 4)) * C + (tid & 15)) * NLAG + v;
#pragma unroll
    for (int u = 0; u < 9; ++u) {
        float ssum = red[(0 * 9 + u) * 256 + tid] + red[(1 * 9 + u) * 256 + tid] +
                     red[(2 * 9 + u) * 256 + tid] + red[(3 * 9 + u) * 256 + tid];
        Ro[u * 9] = ssum;
    }
}

// ---------------------------------------------------------------------------
// crosscorr: P[(n*C+j)*25 + u*5 + v] = sum_{h,w} y[n,0,h,w]*x[n,j,h+u-2,w+v-2]
// ---------------------------------------------------------------------------
__global__ __launch_bounds__(256, 1)
void crosscorr_kernel(const float* __restrict__ x, const float* __restrict__ y,
                      float* __restrict__ P)
{
    const int n = blockIdx.x, j = blockIdx.y, tid = threadIdx.x;
    float acc[25];
#pragma unroll
    for (int l = 0; l < 25; ++l) acc[l] = 0.f;

    const float* yn = y + (size_t)n * H * W;
    const float* xc = x + ((size_t)n * C + j) * H * W;

    for (int p = tid; p < H * W; p += 256) {
        int h = p >> 7, w = p & 127;
        float yv = yn[p];
#pragma unroll
        for (int u = 0; u < 5; ++u) {
            int hr = h + u - 2;
            if ((unsigned)hr < (unsigned)H) {
#pragma unroll
                for (int v = 0; v < 5; ++v) {
                    int wc = w + v - 2;
                    if ((unsigned)wc < (unsigned)W)
                        acc[u * 5 + v] += yv * xc[hr * W + wc];
                }
            }
        }
    }
    __shared__ float red[4][25];
    int lane = tid & 63, wv = tid >> 6;
#pragma unroll
    for (int l = 0; l < 25; ++l) {
        float v = acc[l];
#pragma unroll
        for (int off = 32; off; off >>= 1) v += __shfl_down(v, off);
        if (lane == 0) red[wv][l] = v;
    }
    __syncthreads();
    if (tid < 25)
        P[((size_t)n * C + j) * 25 + tid] = red[0][tid] + red[1][tid] + red[2][tid] + red[3][tid];
}

// ---------------------------------------------------------------------------
// CG solve per sample: (Q + aI) z = P + a*dprev, Q[(i,a,b),(j,c,d)] = R[i,j,4+c-a,4+d-b]
// R staged in LDS (global version was latency-bound at 400 scalar loads/thread/iter).
// ---------------------------------------------------------------------------
__device__ __forceinline__ float block_sum512(float v, float* red, int tid)
{
#pragma unroll
    for (int off = 32; off; off >>= 1) v += __shfl_down(v, off);
    if ((tid & 63) == 0) red[tid >> 6] = v;
    __syncthreads();
    float s = red[0] + red[1] + red[2] + red[3] + red[4] + red[5] + red[6] + red[7];
    __syncthreads();
    return s;
}

__global__ __launch_bounds__(512, 1)
void cg_kernel(const float* __restrict__ R, const float* __restrict__ P,
               const float* __restrict__ dprev, const float* __restrict__ alpha,
               const float* __restrict__ reg, float* __restrict__ Dout, int iters)
{
    __shared__ float Rl[C * C * NLAG];   // 20736 f32 = 81 KB
    __shared__ float zv[M], rv[M], pv[M];
    __shared__ float red[8];
    const int n = blockIdx.x, t = threadIdx.x;
    const float a = alpha[n] * (float)(H * W) * reg[0] / (float)(DS * DS * C);
    const int i = t / 25, ab = t - i * 25, ar = ab / 5, br = ab - ar * 5;

    {   // stage R (coalesced float4)
        const float4* src = (const float4*)(R + (size_t)n * C * C * NLAG);
        float4* dst = (float4*)Rl;
        for (int idx = t; idx < (C * C * NLAG) / 4; idx += 512) dst[idx] = src[idx];
    }
    if (t < M) {
        float rhs = P[(size_t)n * M + t] + a * dprev[(size_t)n * M + t];
        zv[t] = 0.f; rv[t] = rhs; pv[t] = rhs;
    }
    __syncthreads();
    float rr = block_sum512((t < M) ? rv[t] * rv[t] : 0.f, red, t);

    for (int it = 0; it < iters; ++it) {
        float ap = 0.f;
        if (t < M) {
            ap = a * pv[t];
            for (int jj = 0; jj < C; ++jj) {
                const float* Rij = Rl + (i * C + jj) * NLAG;
                const float* pj  = pv + jj * 25;
#pragma unroll
                for (int c = 0; c < 5; ++c) {
                    const int base = (4 + c - ar) * 9 + (4 - br);
#pragma unroll
                    for (int d = 0; d < 5; ++d)
                        ap += Rij[base + d] * pj[c * 5 + d];
                }
            }
        }
        float pAp = block_sum512((t < M) ? pv[t] * ap : 0.f, red, t);
        float al  = (pAp > 1e-30f) ? rr / pAp : 0.f;
        float rn  = 0.f;
        if (t < M) {
            zv[t] += al * pv[t];
            float r2 = rv[t] - al * ap;
            rv[t] = r2;
            rn = r2 * r2;
        }
        float rrn = block_sum512(rn, red, t);
        float be  = (rr > 1e-30f) ? rrn / rr : 0.f;
        rr = rrn;
        if (t < M) pv[t] = rv[t] + be * pv[t];
        __syncthreads();
    }
    if (t < M) Dout[(size_t)n * M + t] = zv[t];
}

// ---------------------------------------------------------------------------
// tiny CNN: h0 = [D2 (16ch), 1/sqrt(beta) (1ch)] 5x5; 6 conv3x3, relu on 1..5,
// residual + h0[:16] after conv6
// ---------------------------------------------------------------------------
__global__ __launch_bounds__(512, 1)
void cnn_kernel(const float* __restrict__ D2, const float* __restrict__ beta,
                const float* __restrict__ w1, const float* __restrict__ b1,
                const float* __restrict__ w2, const float* __restrict__ b2,
                const float* __restrict__ w3, const float* __restrict__ b3,
                const float* __restrict__ w4, const float* __restrict__ b4,
                const float* __restrict__ w5, const float* __restrict__ b5,
                const float* __restrict__ w6, const float* __restrict__ b6,
                float* __restrict__ out)
{
    const int n = blockIdx.x, t = threadIdx.x;
    __shared__ float h0[17 * 25];
    __shared__ float bufA[16 * 25], bufB[16 * 25];
    __shared__ float wl[16 * 17 * 9];
    __shared__ float bl[16];

    if (t < 400)       h0[t] = D2[(size_t)n * M + t];
    else if (t < 425)  h0[t] = rsqrtf(beta[n]);
    __syncthreads();

    const float* ws[6] = {w1, w2, w3, w4, w5, w6};
    const float* bs[6] = {b1, b2, b3, b4, b5, b6};

    for (int l = 0; l < 6; ++l) {
        const int cin = (l == 0) ? 17 : 16;
        const int wsz = 16 * cin * 9;
        for (int idx = t; idx < wsz; idx += 512) wl[idx] = ws[l][idx];
        if (t < 16) bl[t] = bs[l][t];
        __syncthreads();

        const float* in = (l == 0) ? h0 : ((l & 1) ? bufA : bufB);
        float s = 0.f;
        if (t < 400) {
            const int o = t / 25, yy = (t % 25) / 5, xx = t % 5;
            s = bl[o];
            const float* wo = wl + o * cin * 9;
            for (int ci = 0; ci < cin; ++ci) {
                const float* ic = in + ci * 25;
#pragma unroll
                for (int ky = 0; ky < 3; ++ky) {
                    int iy = yy + ky - 1;
                    if ((unsigned)iy < 5u) {
#pragma unroll
                        for (int kx = 0; kx < 3; ++kx) {
                            int ix = xx + kx - 1;
                            if ((unsigned)ix < 5u)
                                s += wo[ci * 9 + ky * 3 + kx] * ic[iy * 5 + ix];
                        }
                    }
                }
            }
            if (l < 5) s = fmaxf(s, 0.f);
            else       s += h0[t];          // residual, channels 0..15 of h0
        }
        __syncthreads();
        if (t < 400) {
            if (l == 5) out[(size_t)n * M + t] = s;
            else if (l & 1) bufB[t] = s;     // l=1 -> B (read by l=2)
            else            bufA[t] = s;     // l=0,2,4 -> A (read by l=1,3,5)
        }
        __syncthreads();
    }
}

// ---------------------------------------------------------------------------
extern "C" void kernel_launch(void* const* d_in, const int* in_sizes, int n_in,
                              void* d_out, int out_size, void* d_ws, size_t ws_size,
                              hipStream_t stream)
{
    (void)in_sizes; (void)n_in; (void)out_size; (void)ws_size;
    const float* x1    = (const float*)d_in[0];
    const float* x2    = (const float*)d_in[1];
    const float* d0    = (const float*)d_in[2];
    const float* y1    = (const float*)d_in[3];
    const float* y2    = (const float*)d_in[4];
    const float* alpha = (const float*)d_in[5];
    const float* beta  = (const float*)d_in[6];
    const float* reg   = (const float*)d_in[7];
    const float* w1 = (const float*)d_in[8];  const float* b1 = (const float*)d_in[9];
    const float* w2 = (const float*)d_in[10]; const float* b2 = (const float*)d_in[11];
    const float* w3 = (const float*)d_in[12]; const float* b3 = (const float*)d_in[13];
    const float* w4 = (const float*)d_in[14]; const float* b4 = (const float*)d_in[15];
    const float* w5 = (const float*)d_in[16]; const float* b5 = (const float*)d_in[17];
    const float* w6 = (const float*)d_in[18]; const float* b6 = (const float*)d_in[19];
    float* out = (float*)d_out;

    float* ws = (float*)d_ws;
    const size_t RSZ = (size_t)NS * C * C * NLAG;   // 663552
    float* R1 = ws;
    float* R2 = R1 + RSZ;
    float* P1 = R2 + RSZ;
    float* P2 = P1 + (size_t)NS * M;
    float* D1 = P2 + (size_t)NS * M;
    float* D2 = D1 + (size_t)NS * M;

    autocorr_mfma<<<dim3(NS, 9, 2), 256, 0, stream>>>(x1, x2, R1, R2);
    crosscorr_kernel<<<dim3(NS, C), 256, 0, stream>>>(x1, y1, P1);
    crosscorr_kernel<<<dim3(NS, C), 256, 0, stream>>>(x2, y2, P2);
    cg_kernel<<<NS, 512, 0, stream>>>(R1, P1, d0, alpha, reg, D1, 5);
    cg_kernel<<<NS, 512, 0, stream>>>(R2, P2, D1, alpha, reg, D2, 9);
    cnn_kernel<<<NS, 512, 0, stream>>>(D2, beta, w1, b1, w2, b2, w3, b3,
                                       w4, b4, w5, b5, w6, b6, out);
}